// Round 13
// baseline (150.134 us; speedup 1.0000x reference)
//
#include <hip/hip_runtime.h>

// R13 = R8 (2 rows/wave, tail weights loaded once feeding 2 fma chains; best
// measured kernel ~27us) x R12 (channel-per-lane token loop, 1-reg
// accumulators; clean 33us). Token records packed [p0 p1 p2 c0 c1 _ _ _]:
// per iteration 1 ds_read_b128 + 1 ds_read_b32 + 9 VALU covers one token of
// EACH row (half-wave h owns row h, shared instruction stream, 2 distinct
// LDS addrs/wave = free aliasing). Grid 2048 x 64 (8 waves/CU).

#define BDIM 64
#define S 256

__global__ __launch_bounds__(BDIM)
void mlpreg_kernel(const float* __restrict__ cont_p,
                   const float* __restrict__ cont_c,
                   const int* __restrict__ cat_p,
                   const int* __restrict__ cat_c,
                   const int* __restrict__ lengths,
                   const float* __restrict__ w_p1, const float* __restrict__ b_p1,
                   const float* __restrict__ w_p2, const float* __restrict__ b_p2,
                   const float* __restrict__ w_c1, const float* __restrict__ b_c1,
                   const float* __restrict__ w_c2, const float* __restrict__ b_c2,
                   const float* __restrict__ emb_g,  const float* __restrict__ emb_k,
                   const float* __restrict__ emb_pr, const float* __restrict__ emb_j,
                   const float* __restrict__ emb_r,  const float* __restrict__ emb_pl,
                   const float* __restrict__ emb_a,
                   const float* __restrict__ w_fc1, const float* __restrict__ b_fc1,
                   const float* __restrict__ w_fc2, const float* __restrict__ b_fc2,
                   float* __restrict__ out)
{
    __shared__ __align__(16) float sTok[2][S * 8];   // 16 KB, [p0 p1 p2 c0 c1 _ _ _]
    __shared__ int   hist[2][96];     // job@0(11) rep@11(34) place@45(19) add@64(31)
    __shared__ float sPacc[2][64];
    __shared__ __align__(16) float sPool[2][128];    // [ep | ec | hp2 | hc2]

    const int lane = threadIdx.x;
    const int b0 = blockIdx.x * 2, b1 = b0 + 1;
    int2 ll = *(const int2*)&lengths[b0];
    int L0 = ll.x; L0 = (L0 < 1) ? 1 : (L0 > S ? S : L0);
    int L1 = ll.y; L1 = (L1 < 1) ? 1 : (L1 > S ? S : L1);
    const float L0f = (float)L0, L1f = (float)L1;
    const float invL0 = 1.0f / L0f, invL1 = 1.0f / L1f;

    // zero hist (192 ints; same-wave LDS program order precedes atomics)
    ((int*)hist)[lane]       = 0;
    ((int*)hist)[64 + lane]  = 0;
    ((int*)hist)[128 + lane] = 0;

    const int ch = lane & 31, h = lane >> 5;
    // per-lane first-layer weights for BOTH feature groups (7 regs)
    const float wp0 = w_p1[ch], wp1 = w_p1[32 + ch], wp2 = w_p1[64 + ch], bp = b_p1[ch];
    const float wc0 = w_c1[ch], wc1 = w_c1[32 + ch], bc = b_c1[ch];

    const float* gp[2] = { cont_p + (size_t)b0 * (S * 3), cont_p + (size_t)b1 * (S * 3) };
    const float* gc[2] = { cont_c + (size_t)b0 * (S * 2), cont_c + (size_t)b1 * (S * 2) };
    const int*   kp[2] = { cat_p  + (size_t)b0 * (S * 5), cat_p  + (size_t)b1 * (S * 5) };
    const int*   kc[2] = { cat_c  + (size_t)b0 * (S * 2), cat_c  + (size_t)b1 * (S * 2) };
    const int    Ls[2] = { L0, L1 };

    // ---- stage token records (coalesced global reads, scatter ds writes) ----
    #pragma unroll
    for (int r = 0; r < 2; ++r) {
        const int n3 = 3 * Ls[r], n2 = 2 * Ls[r];
        for (int i = lane; i < n3; i += BDIM) {
            int t = i / 3, c = i - 3 * t;
            sTok[r][t * 8 + c] = gp[r][i];
        }
        for (int i = lane; i < n2; i += BDIM) {
            int t = i >> 1, c = i & 1;
            sTok[r][t * 8 + 3 + c] = gc[r][i];
        }
    }

    // ---- categorical pass: packed binary sums + hist atomics ----
    int pk0 = 0, pk1 = 0;
    #pragma unroll
    for (int r = 0; r < 2; ++r) {
        #pragma unroll
        for (int blk = 0; blk < 4; ++blk) {
            if (Ls[r] > blk * 64) {
                int t = blk * 64 + lane;
                if (t < Ls[r]) {
                    int v0 = kp[r][5 * t], v1 = kp[r][5 * t + 1], v2 = kp[r][5 * t + 2],
                        v3 = kp[r][5 * t + 3], v4 = kp[r][5 * t + 4];
                    int2 q = *(const int2*)&kc[r][2 * t];
                    int add = v0 + (v1 << 10) + (v2 << 20);
                    if (r == 0) pk0 += add; else pk1 += add;
                    atomicAdd(&hist[r][v3], 1);
                    atomicAdd(&hist[r][11 + v4], 1);
                    atomicAdd(&hist[r][45 + q.x], 1);
                    atomicAdd(&hist[r][64 + q.y], 1);
                }
            }
        }
    }
    #pragma unroll
    for (int d = 32; d; d >>= 1) {
        pk0 += __shfl_xor(pk0, d);
        pk1 += __shfl_xor(pk1, d);
    }
    const float sg0 = (float)(pk0 & 1023), sk0 = (float)((pk0 >> 10) & 1023),
                sp0 = (float)(pk0 >> 20);
    const float sg1 = (float)(pk1 & 1023), sk1 = (float)((pk1 >> 10) & 1023),
                sp1 = (float)(pk1 >> 20);
    __syncthreads();   // B1: sTok + hist visible wave-wide

    // ---- token loop: half-wave h owns row h; 1 b128 + 1 b32 + 9 VALU/iter ----
    {
        const float* tok  = sTok[h];
        const int    myL  = h ? L1 : L0;
        const float  invr = h ? invL1 : invL0;
        float accP = 0.f, accC = 0.f;
        #pragma unroll 2
        for (int t = 0; t < myL; ++t) {
            float4 v  = *(const float4*)&tok[t * 8];
            float  c1 = tok[t * 8 + 4];
            accP += fmaxf(fmaf(v.x, wp0, fmaf(v.y, wp1, fmaf(v.z, wp2, bp))), 0.f);
            accC += fmaxf(fmaf(v.w, wc0, fmaf(c1, wc1, bc)), 0.f);
        }
        sPacc[h][ch]      = accP * invr;
        sPacc[h][32 + ch] = accC * invr;
    }
    __syncthreads();   // B2: sPacc ready

    // ---- tail: every weight loaded once, FMA'd into both rows (R8) ----
    if (h == 0) {
        // ep: binaries + job(11) + rep(34)
        float g0 = emb_g[ch],  g1 = emb_g[32 + ch];
        float k0 = emb_k[ch],  k1 = emb_k[32 + ch];
        float p0 = emb_pr[ch], p1 = emb_pr[32 + ch];
        float A0 = fmaf(L0f - sg0, g0, sg0 * g1) + fmaf(L0f - sk0, k0, sk0 * k1)
                 + fmaf(L0f - sp0, p0, sp0 * p1);
        float A1 = fmaf(L1f - sg1, g0, sg1 * g1) + fmaf(L1f - sk1, k0, sk1 * k1)
                 + fmaf(L1f - sp1, p0, sp1 * p1);
        #pragma unroll
        for (int r = 0; r < 11; ++r) {
            float w = emb_j[r * 32 + ch];
            A0 = fmaf((float)hist[0][r], w, A0);
            A1 = fmaf((float)hist[1][r], w, A1);
        }
        #pragma unroll
        for (int r = 0; r < 34; ++r) {
            float w = emb_r[r * 32 + ch];
            A0 = fmaf((float)hist[0][11 + r], w, A0);
            A1 = fmaf((float)hist[1][11 + r], w, A1);
        }
        sPool[0][ch] = A0 * (invL0 * 0.2f);
        sPool[1][ch] = A1 * (invL1 * 0.2f);

        float v0 = b_p2[ch], v1 = v0;
        #pragma unroll
        for (int k = 0; k < 32; ++k) {
            float w = w_p2[k * 32 + ch];
            v0 = fmaf(sPacc[0][k], w, v0);
            v1 = fmaf(sPacc[1][k], w, v1);
        }
        sPool[0][64 + ch] = v0;
        sPool[1][64 + ch] = v1;
    } else {
        float A0 = 0.f, A1 = 0.f;
        #pragma unroll
        for (int r = 0; r < 19; ++r) {
            float w = emb_pl[r * 32 + ch];
            A0 = fmaf((float)hist[0][45 + r], w, A0);
            A1 = fmaf((float)hist[1][45 + r], w, A1);
        }
        #pragma unroll
        for (int r = 0; r < 31; ++r) {
            float w = emb_a[r * 32 + ch];
            A0 = fmaf((float)hist[0][64 + r], w, A0);
            A1 = fmaf((float)hist[1][64 + r], w, A1);
        }
        sPool[0][32 + ch] = A0 * (invL0 * 0.5f);
        sPool[1][32 + ch] = A1 * (invL1 * 0.5f);

        float v0 = b_c2[ch], v1 = v0;
        #pragma unroll
        for (int k = 0; k < 32; ++k) {
            float w = w_c2[k * 32 + ch];
            v0 = fmaf(sPacc[0][32 + k], w, v0);
            v1 = fmaf(sPacc[1][32 + k], w, v1);
        }
        sPool[0][96 + ch] = v0;
        sPool[1][96 + ch] = v1;
    }
    __syncthreads();   // B3: sPool ready

    // ---- fc1 (one output per lane, both rows, float4 LDS broadcasts) ----
    {
        const int o = lane;
        float x0 = b_fc1[o], y0 = 0.f;
        float x1 = x0,       y1 = 0.f;
        #pragma unroll
        for (int k4 = 0; k4 < 32; ++k4) {
            float4 u = *(const float4*)&sPool[0][4 * k4];
            float4 s = *(const float4*)&sPool[1][4 * k4];
            float wa = w_fc1[(size_t)(4 * k4 + 0) * 64 + o];
            float wb = w_fc1[(size_t)(4 * k4 + 1) * 64 + o];
            float wc = w_fc1[(size_t)(4 * k4 + 2) * 64 + o];
            float wd = w_fc1[(size_t)(4 * k4 + 3) * 64 + o];
            x0 = fmaf(u.x, wa, x0); y0 = fmaf(u.y, wb, y0);
            x0 = fmaf(u.z, wc, x0); y0 = fmaf(u.w, wd, y0);
            x1 = fmaf(s.x, wa, x1); y1 = fmaf(s.y, wb, y1);
            x1 = fmaf(s.z, wc, x1); y1 = fmaf(s.w, wd, y1);
        }
        float h0 = fmaxf(x0 + y0, 0.f);
        float h1 = fmaxf(x1 + y1, 0.f);

        // ---- fc2 butterfly + float4 store for both rows ----
        float wa = w_fc2[2 * o], wb = w_fc2[2 * o + 1];
        float q00 = h0 * wa, q01 = h0 * wb, q10 = h1 * wa, q11 = h1 * wb;
        #pragma unroll
        for (int d = 32; d; d >>= 1) {
            q00 += __shfl_xor(q00, d); q01 += __shfl_xor(q01, d);
            q10 += __shfl_xor(q10, d); q11 += __shfl_xor(q11, d);
        }
        if (lane == 0) {
            float bb0 = b_fc2[0], bb1 = b_fc2[1];
            float4 o4;
            o4.x = fmaxf(q00 + bb0, 0.f);
            o4.y = fmaxf(q01 + bb1, 0.f);
            o4.z = fmaxf(q10 + bb0, 0.f);
            o4.w = fmaxf(q11 + bb1, 0.f);
            *(float4*)&out[(size_t)b0 * 2] = o4;
        }
    }
}

extern "C" void kernel_launch(void* const* d_in, const int* in_sizes, int n_in,
                              void* d_out, int out_size, void* d_ws, size_t ws_size,
                              hipStream_t stream) {
    const float* cont_p = (const float*)d_in[0];
    const float* cont_c = (const float*)d_in[1];
    const int*   cat_p  = (const int*)d_in[2];
    const int*   cat_c  = (const int*)d_in[3];
    const int*   lens   = (const int*)d_in[4];
    const float* w_p1   = (const float*)d_in[5];
    const float* b_p1   = (const float*)d_in[6];
    const float* w_p2   = (const float*)d_in[7];
    const float* b_p2   = (const float*)d_in[8];
    const float* w_c1   = (const float*)d_in[9];
    const float* b_c1   = (const float*)d_in[10];
    const float* w_c2   = (const float*)d_in[11];
    const float* b_c2   = (const float*)d_in[12];
    const float* emb_g  = (const float*)d_in[13];
    const float* emb_k  = (const float*)d_in[14];
    const float* emb_pr = (const float*)d_in[15];
    const float* emb_j  = (const float*)d_in[16];
    const float* emb_r  = (const float*)d_in[17];
    const float* emb_pl = (const float*)d_in[18];
    const float* emb_a  = (const float*)d_in[19];
    const float* w_fc1  = (const float*)d_in[20];
    const float* b_fc1  = (const float*)d_in[21];
    const float* w_fc2  = (const float*)d_in[22];
    const float* b_fc2  = (const float*)d_in[23];
    float* out = (float*)d_out;

    hipLaunchKernelGGL(mlpreg_kernel, dim3(2048), dim3(BDIM), 0, stream,
                       cont_p, cont_c, cat_p, cat_c, lens,
                       w_p1, b_p1, w_p2, b_p2, w_c1, b_c1, w_c2, b_c2,
                       emb_g, emb_k, emb_pr, emb_j, emb_r, emb_pl, emb_a,
                       w_fc1, b_fc1, w_fc2, b_fc2, out);
}